// Round 6
// baseline (255.609 us; speedup 1.0000x reference)
//
#include <hip/hip_runtime.h>
#include <hip/hip_fp16.h>

// DGCF single-layer, 2 routing iters (MI355X). fp32 in / fp32 out.
// R20: scatter write-amp round 2. R18's int2 csr_ht scatter = 800K x 8B
// scattered stores into 6.4MB (> 4MB per-XCD L2) -> partial dirty-line
// evictions ~51MB write-back. Split:
//  - csr_tail: tail-only 4B scattered store into 3.2MB (fits per-XCD L2;
//    ~16 hits/line accumulate before one evict -> ~26MB write-back).
//  - csr_head: heads are CSR-sorted by construction -> written COALESCED
//    inside zacc (lane-strided over [s0,s1), zero extra dispatch).
// zacc/outk now read 4B/edge index data (was 8B). attdot reads two
// sequential streams head[]/tail[].
// Unchanged from R19 (passing): single-visit outk over Y1i[n][64],
// interleaved s4, 2-node x 32-lane zacc/outk shape, rank-from-count
// atomic-free scatter, attdot one-edge-per-lane, scans, Ytab/Ttab.

#define NUSERS 30000
#define NN     60000
#define EE     800000
#define SCAN_B ((NN + 255) / 256)       // 235 scan blocks
#define EV_B   ((EE / 4 + 255) / 256)   // 782 int4 edge blocks
#define NW1_B  ((NN + 1 + 3) / 4)       // 15001 node blocks (incl zero row)
#define N8_B   ((NN + 7) / 8)           // 7500 blocks (8 nodes per block)

__device__ __forceinline__ float getX(const float* __restrict__ Gu,
                                      const float* __restrict__ Gi,
                                      int n, int c) {
    return (n < NUSERS) ? Gu[n * 64 + c] : Gi[(n - NUSERS) * 64 + c];
}

__device__ __forceinline__ int clampN(int n) {
    return ((unsigned)n < (unsigned)NN) ? n : 0;
}

__device__ __forceinline__ __half2 bch2(float f) {
    return __builtin_bit_cast(__half2, f);
}

// ---- CSR build ----

// Count degrees AND record each edge's rank within its head bucket
// (atomicAdd return value). rank written coalesced (int4).
__global__ void edge_count(const int* __restrict__ eh, int* __restrict__ deg0,
                           int* __restrict__ rank) {
    int e4 = (blockIdx.x * blockDim.x + threadIdx.x) * 4;
    if (e4 >= EE) return;
    int4 h = *(const int4*)(eh + e4);
    int4 r;
    r.x = atomicAdd(&deg0[clampN(h.x)], 1);
    r.y = atomicAdd(&deg0[clampN(h.y)], 1);
    r.z = atomicAdd(&deg0[clampN(h.z)], 1);
    r.w = atomicAdd(&deg0[clampN(h.w)], 1);
    *(int4*)(rank + e4) = r;
}

// In-block exclusive scan of 256 ints.
__global__ void scan_local(const int* __restrict__ deg0, int* __restrict__ offsets,
                           int* __restrict__ bsum) {
    int gid = blockIdx.x * 256 + threadIdx.x;
    int lane = threadIdx.x & 63, w = threadIdx.x >> 6;
    int vdeg = (gid < NN) ? deg0[gid] : 0;
    int x = vdeg;
    #pragma unroll
    for (int d = 1; d < 64; d <<= 1) {
        int y = __shfl_up(x, d, 64);
        if (lane >= d) x += y;
    }
    __shared__ int wsum[4];
    if (lane == 63) wsum[w] = x;
    __syncthreads();
    int wpre = 0;
    #pragma unroll
    for (int j = 0; j < 4; ++j) wpre += (j < w) ? wsum[j] : 0;
    int incl = x + wpre;
    if (gid < NN) offsets[gid] = incl - vdeg;
    if (threadIdx.x == 255) bsum[blockIdx.x] = incl;
}

// Each block re-scans the 235 block sums (cheap) and adds its own prefix.
__global__ void scan_add2(int* __restrict__ offsets, const int* __restrict__ bsum) {
    int tid = threadIdx.x, lane = tid & 63, w = tid >> 6;
    int vv = (tid < SCAN_B) ? bsum[tid] : 0;
    int x = vv;
    #pragma unroll
    for (int d = 1; d < 64; d <<= 1) {
        int y = __shfl_up(x, d, 64);
        if (lane >= d) x += y;
    }
    __shared__ int wsum[4];
    __shared__ int bpre;
    if (lane == 63) wsum[w] = x;
    __syncthreads();
    int wpre = 0;
    #pragma unroll
    for (int j = 0; j < 4; ++j) wpre += (j < w) ? wsum[j] : 0;
    if (tid == blockIdx.x) bpre = x + wpre - vv;   // exclusive prefix of this block
    __syncthreads();
    int gid = blockIdx.x * 256 + tid;
    if (gid < NN) offsets[gid] += bpre;
    if (gid == 0) offsets[NN] = EE;
}

// ---- merged dispatch: edge_scatter (blocks [0,EV_B)) || prep0s (rest) ----
// scatter: atomic-free permute; ONE scattered 4B (tail) store per edge
// into a 3.2MB array that fits per-XCD L2 (write-combining friendly).
// prep0s: node-interleaved Ytab/Ttab rows (64 halfs = all intents), zero
// row at n == NN.
__global__ void scatter_prep(const int* __restrict__ eh, const int* __restrict__ et,
                             const int* __restrict__ rank,
                             const int* __restrict__ offsets,
                             int* __restrict__ csr_tail,
                             const float* __restrict__ Gu, const float* __restrict__ Gi,
                             const int* __restrict__ deg0,
                             __half* __restrict__ Ytab, __half* __restrict__ Ttab) {
    if (blockIdx.x < EV_B) {
        int e4 = (blockIdx.x * 256 + threadIdx.x) * 4;
        if (e4 >= EE) return;
        int4 h = *(const int4*)(eh + e4);
        int4 t = *(const int4*)(et + e4);
        int4 r = *(const int4*)(rank + e4);
        int s0 = offsets[clampN(h.x)] + r.x;
        if ((unsigned)s0 < EE) csr_tail[s0] = clampN(t.x);
        int s1 = offsets[clampN(h.y)] + r.y;
        if ((unsigned)s1 < EE) csr_tail[s1] = clampN(t.y);
        int s2 = offsets[clampN(h.z)] + r.z;
        if ((unsigned)s2 < EE) csr_tail[s2] = clampN(t.z);
        int s3 = offsets[clampN(h.w)] + r.w;
        if ((unsigned)s3 < EE) csr_tail[s3] = clampN(t.w);
    } else {
        int n = (blockIdx.x - EV_B) * 4 + (threadIdx.x >> 6);
        if (n > NN) return;
        int lane = threadIdx.x & 63;            // lane == channel c
        float x = (n < NN) ? getX(Gu, Gi, n, lane) : 0.f;
        float sx = x * x;
        #pragma unroll
        for (int m = 1; m < 16; m <<= 1) sx += __shfl_xor(sx, m, 64);  // 16-ch intent group
        float invx = rsqrtf(fmaxf(sx, 1e-12f));
        float d0 = rsqrtf(fmaxf(0.25f * (float)((n < NN) ? deg0[n] : 1), 1e-30f));
        size_t a = (size_t)n * 64 + lane;
        Ytab[a] = __float2half(d0 * x);          // iter-0 Y (scores==0.25 folded)
        Ttab[a] = __float2half(tanhf(x * invx)); // tanh of l2norm(x) per intent
    }
}

// ---- zacc: Z1 accumulate + per-intent l2norm -> ZN[n][64] ----
// wave = 2 nodes x 32 half2-ch lanes; unroll-4 -> 8 full-line gathers in
// flight per wave. Also fills csr_head coalesced (heads are CSR-sorted:
// head[s] == n for s in [s0,s1)) for attdot.
__global__ void zacc(const int* __restrict__ offsets, const int* __restrict__ csr_tail,
                     const __half* __restrict__ Ytab, __half* __restrict__ ZN,
                     int* __restrict__ csr_head) {
    int tid = threadIdx.x;
    int n = blockIdx.x * 8 + (tid >> 5);
    if (n >= NN) return;
    int cc = tid & 31;                           // half2-channel (2cc, 2cc+1)
    int s0 = offsets[n], s1 = offsets[n + 1];
    for (int k = s0 + cc; k < s1; k += 32) csr_head[k] = n;  // coalesced head fill
    float accx = 0.f, accy = 0.f;
    for (int base = s0; base < s1; base += 4) {
        #pragma unroll
        for (int u = 0; u < 4; ++u) {
            int kk = base + u;
            bool act = kk < s1;
            int kc = act ? kk : s0;              // in-bounds; deg >= 1 always
            int t = act ? csr_tail[kc] : NN;     // NN = zero row
            __half2 y = *(const __half2*)(Ytab + (size_t)t * 64 + cc * 2);
            float2 yf = __half22float2(y);
            accx += yf.x; accy += yf.y;
        }
    }
    // per-intent l2 norm: 8-lane group = 16 channels = 1 intent
    float ss = accx * accx + accy * accy;
    ss += __shfl_xor(ss, 1, 64);
    ss += __shfl_xor(ss, 2, 64);
    ss += __shfl_xor(ss, 4, 64);
    float inv = rsqrtf(fmaxf(ss, 1e-12f));
    *(__half2*)(ZN + (size_t)n * 64 + cc * 2) =
        __floats2half2_rn(accx * inv, accy * inv);
}

// ---- attdot: per-edge attention dots, one edge per lane, no shuffles ----
// v stored interleaved: v4[k][4] halfs (one 8B store per edge).
__global__ void attdot(const int* __restrict__ csr_head, const int* __restrict__ csr_tail,
                       const __half* __restrict__ ZN, const __half* __restrict__ Ttab,
                       __half* __restrict__ v4) {
    int k = blockIdx.x * 256 + threadIdx.x;
    if (k >= EE) return;
    int h = csr_head[k], t = csr_tail[k];
    const float4* zp = (const float4*)(ZN + (size_t)h * 64);
    const float4* tp = (const float4*)(Ttab + (size_t)t * 64);
    float dot[4];
    #pragma unroll
    for (int i = 0; i < 4; ++i) {
        float4 za = zp[2 * i], zb = zp[2 * i + 1];
        float4 ta = tp[2 * i], tb = tp[2 * i + 1];
        __half2 acc = __floats2half2_rn(0.f, 0.f);
        acc = __hfma2(bch2(za.x), bch2(ta.x), acc);
        acc = __hfma2(bch2(za.y), bch2(ta.y), acc);
        acc = __hfma2(bch2(za.z), bch2(ta.z), acc);
        acc = __hfma2(bch2(za.w), bch2(ta.w), acc);
        acc = __hfma2(bch2(zb.x), bch2(tb.x), acc);
        acc = __hfma2(bch2(zb.y), bch2(tb.y), acc);
        acc = __hfma2(bch2(zb.z), bch2(tb.z), acc);
        acc = __hfma2(bch2(zb.w), bch2(tb.w), acc);
        float2 f = __half22float2(acc);
        dot[i] = f.x + f.y;
    }
    __half2 o01 = __floats2half2_rn(dot[0], dot[1]);
    __half2 o23 = __floats2half2_rn(dot[2], dot[3]);
    int2 st;
    st.x = __builtin_bit_cast(int, o01);
    st.y = __builtin_bit_cast(int, o23);
    *(int2*)(v4 + (size_t)k * 4) = st;
}

// ---- fused softmax + dcol1 + Y1/scores build (wave per node) ----
// Writes interleaved s4[k][4] (one 8B store) and Y1i[n][64] (one coalesced
// 128B row; channel == lane).
__global__ void sm_dcol_y1(const int* __restrict__ offsets, const __half* __restrict__ v4,
                           __half* __restrict__ s4, float* __restrict__ dcol1,
                           const float* __restrict__ Gu, const float* __restrict__ Gi,
                           __half* __restrict__ Y1i) {
    int n = blockIdx.x * 4 + (threadIdx.x >> 6);
    if (n >= NN) return;
    int lane = threadIdx.x & 63;
    int s0 = offsets[n], s1 = offsets[n + 1];
    float sum0 = 0.f, sum1 = 0.f, sum2 = 0.f, sum3 = 0.f;
    for (int k = s0 + lane; k < s1; k += 64) {
        int2 raw = *(const int2*)(v4 + (size_t)k * 4);
        __half2 p01 = __builtin_bit_cast(__half2, raw.x);
        __half2 p23 = __builtin_bit_cast(__half2, raw.y);
        float2 fa = __half22float2(p01), fb = __half22float2(p23);
        float v0 = fa.x, v1 = fa.y, v2 = fb.x, v3 = fb.y;
        float mx = fmaxf(fmaxf(v0, v1), fmaxf(v2, v3));
        float e0 = __expf(v0 - mx), e1 = __expf(v1 - mx);
        float e2 = __expf(v2 - mx), e3 = __expf(v3 - mx);
        float inv = 1.f / (e0 + e1 + e2 + e3);
        e0 *= inv; e1 *= inv; e2 *= inv; e3 *= inv;
        __half2 q01 = __floats2half2_rn(e0, e1);
        __half2 q23 = __floats2half2_rn(e2, e3);
        int2 st;
        st.x = __builtin_bit_cast(int, q01);
        st.y = __builtin_bit_cast(int, q23);
        *(int2*)(s4 + (size_t)k * 4) = st;
        sum0 += e0; sum1 += e1; sum2 += e2; sum3 += e3;
    }
    #pragma unroll
    for (int m = 1; m < 64; m <<= 1) {
        sum0 += __shfl_xor(sum0, m, 64);
        sum1 += __shfl_xor(sum1, m, 64);
        sum2 += __shfl_xor(sum2, m, 64);
        sum3 += __shfl_xor(sum3, m, 64);
    }
    int i = lane >> 4;                           // intent of channel 'lane'
    float dsel = (i == 0) ? sum0 : (i == 1) ? sum1 : (i == 2) ? sum2 : sum3;
    float d = rsqrtf(fmaxf(dsel, 1e-30f));
    if (lane < 4) {
        float ds = (lane == 0) ? sum0 : (lane == 1) ? sum1 : (lane == 2) ? sum2 : sum3;
        dcol1[n * 4 + lane] = rsqrtf(fmaxf(ds, 1e-30f));
    }
    float x = getX(Gu, Gi, n, lane);
    Y1i[(size_t)n * 64 + lane] = __float2half(d * x);
}

// ---- output pass: Z2 gather + finalize ----
// wave = 2 nodes x 32 half2-ch lanes (all 4 intents at once). Per edge:
// broadcast csr_tail + s4 (lane extracts its intent's half), 32 lanes
// gather one full 128B Y1i row. Single visit per edge. float2 store.
__global__ void outk(const int* __restrict__ offsets, const int* __restrict__ csr_tail,
                     const __half* __restrict__ Y1i, const __half* __restrict__ s4,
                     const float* __restrict__ dcol1,
                     const float* __restrict__ Gu, const float* __restrict__ Gi,
                     float* __restrict__ out) {
    int tid = threadIdx.x;
    int n = blockIdx.x * 8 + (tid >> 5);
    if (n >= NN) return;
    int cc = tid & 31;                           // half2-channel (2cc, 2cc+1)
    int s0 = offsets[n], s1 = offsets[n + 1];
    float accx = 0.f, accy = 0.f;
    for (int base = s0; base < s1; base += 4) {
        #pragma unroll
        for (int u = 0; u < 4; ++u) {
            int kk = base + u;
            bool act = kk < s1;
            int kc = act ? kk : s0;              // in-bounds; deg >= 1 always
            int t = csr_tail[kc];
            int2 raw = *(const int2*)(s4 + (size_t)kc * 4);
            int word = (cc & 16) ? raw.y : raw.x;
            unsigned short us = (unsigned short)(word >> ((cc & 8) ? 16 : 0));
            float s = act ? __half2float(__builtin_bit_cast(__half, us)) : 0.f;
            __half2 y = *(const __half2*)(Y1i + (size_t)t * 64 + cc * 2);
            float2 yf = __half22float2(y);
            accx = fmaf(s, yf.x, accx);
            accy = fmaf(s, yf.y, accy);
        }
    }
    float d = dcol1[n * 4 + (cc >> 3)];
    int ch = cc * 2;
    const float* xr = (n < NUSERS) ? (Gu + (size_t)n * 64 + ch)
                                   : (Gi + (size_t)(n - NUSERS) * 64 + ch);
    float2 x2 = *(const float2*)xr;
    float2 o;
    o.x = 0.5f * (x2.x + d * accx);
    o.y = 0.5f * (x2.y + d * accy);
    *(float2*)(out + (size_t)n * 64 + ch) = o;
}

// ---- launch ----

extern "C" void kernel_launch(void* const* d_in, const int* in_sizes, int n_in,
                              void* d_out, int out_size, void* d_ws, size_t ws_size,
                              hipStream_t stream) {
    const float* Gu = (const float*)d_in[0];
    const float* Gi = (const float*)d_in[1];
    const int* eh = (const int*)d_in[2];
    const int* et = (const int*)d_in[3];
    float* out = (float*)d_out;

    char* p = (char*)d_ws;
    __half* v4       = (__half*)p;     p += (size_t)EE * 4 * 2;       // 6.4 MB
    __half* s4       = (__half*)p;     p += (size_t)EE * 4 * 2;       // 6.4 MB
    int*    csr_tail = (int*)p;        p += (size_t)EE * 4;           // 3.2 MB
    int*    csr_head = (int*)p;        p += (size_t)EE * 4;           // 3.2 MB
    int*    rank     = (int*)p;        p += (size_t)EE * 4;           // 3.2 MB
    int*    offsets  = (int*)p;        p += ((size_t)(NN + 1) * 4 + 15) / 16 * 16;
    int*    deg0     = (int*)p;        p += (size_t)NN * 4;
    int*    bsum     = (int*)p;        p += ((size_t)SCAN_B * 4 + 15) / 16 * 16;
    float*  dcol1    = (float*)p;      p += (size_t)NN * 4 * 4;
    __half* Ytab     = (__half*)p;     p += (size_t)(NN + 1) * 64 * 2; // 7.68 MB
    __half* Ttab     = (__half*)p;     p += (size_t)(NN + 1) * 64 * 2; // 7.68 MB
    __half* ZN       = (__half*)p;     // NN*64*2 = 7.68 MB -> total ~47 MB
    __half* Y1i      = Ytab;           // aliases Ytab (dead after zacc)

    const int nw_blocks = (NN + 3) / 4;

    // CSR build (rank-from-count: no cursor, no scatter atomics)
    hipMemsetAsync(deg0, 0, NN * sizeof(int), stream);
    edge_count<<<EV_B, 256, 0, stream>>>(eh, deg0, rank);
    scan_local<<<SCAN_B, 256, 0, stream>>>(deg0, offsets, bsum);
    scan_add2<<<SCAN_B, 256, 0, stream>>>(offsets, bsum);

    // atomic-free edge permute (tail-only 4B scatter) || prep tables
    scatter_prep<<<EV_B + NW1_B, 256, 0, stream>>>(eh, et, rank, offsets, csr_tail,
                                                   Gu, Gi, deg0, Ytab, Ttab);

    // iter 0: Z1 accumulate + norm + coalesced head fill, then per-edge dots
    zacc<<<N8_B, 256, 0, stream>>>(offsets, csr_tail, Ytab, ZN, csr_head);
    attdot<<<(EE + 255) / 256, 256, 0, stream>>>(csr_head, csr_tail, ZN, Ttab, v4);

    // softmax + dcol1 + interleaved s4/Y1i in one pass
    sm_dcol_y1<<<nw_blocks, 256, 0, stream>>>(offsets, v4, s4, dcol1, Gu, Gi, Y1i);

    // iter 1 propagate + finalize: single visit per edge, full-line gathers
    outk<<<N8_B, 256, 0, stream>>>(offsets, csr_tail, Y1i, s4, dcol1, Gu, Gi, out);
}

// Round 7
// 252.717 us; speedup vs baseline: 1.0114x; 1.0114x over previous
//
#include <hip/hip_runtime.h>
#include <hip/hip_fp16.h>

// DGCF single-layer, 2 routing iters (MI355X). fp32 in / fp32 out.
// R21: R20 neutral (254.9->255.6us): scatter write-combining theory didn't
// move the total; all our kernels now < 44us (below harness fill kernels).
// Remaining structural redundancy: softmax over intents is PER-EDGE
// (axis=0 = the 4 intents, no cross-edge coupling), yet we round-tripped
// raw dots v4 through HBM (6.4MB write + 6.4MB read) and re-did softmax
// inside the node-parallel kernel. Fused:
//  - attdot_sm: per-edge dots -> in-lane softmax over 4 intents (shift-
//    invariant, so the A=1+dot offset drops) -> store s4 directly.
//    v4 deleted.
//  - deg_y1: slim sm_dcol_y1: per node sum s4 over bucket (no exp/max),
//    butterfly, write dcol1 + coalesced Y1i row.
// Unchanged from R20 (passing): rank-from-count atomic-free scatter,
// tail-only 4B scatter, zacc 2-node x 32-lane + coalesced head fill,
// single-visit outk over Y1i[n][64], scans, Ytab/Ttab.

#define NUSERS 30000
#define NN     60000
#define EE     800000
#define SCAN_B ((NN + 255) / 256)       // 235 scan blocks
#define EV_B   ((EE / 4 + 255) / 256)   // 782 int4 edge blocks
#define NW1_B  ((NN + 1 + 3) / 4)       // 15001 node blocks (incl zero row)
#define N8_B   ((NN + 7) / 8)           // 7500 blocks (8 nodes per block)

__device__ __forceinline__ float getX(const float* __restrict__ Gu,
                                      const float* __restrict__ Gi,
                                      int n, int c) {
    return (n < NUSERS) ? Gu[n * 64 + c] : Gi[(n - NUSERS) * 64 + c];
}

__device__ __forceinline__ int clampN(int n) {
    return ((unsigned)n < (unsigned)NN) ? n : 0;
}

__device__ __forceinline__ __half2 bch2(float f) {
    return __builtin_bit_cast(__half2, f);
}

// ---- CSR build ----

// Count degrees AND record each edge's rank within its head bucket
// (atomicAdd return value). rank written coalesced (int4).
__global__ void edge_count(const int* __restrict__ eh, int* __restrict__ deg0,
                           int* __restrict__ rank) {
    int e4 = (blockIdx.x * blockDim.x + threadIdx.x) * 4;
    if (e4 >= EE) return;
    int4 h = *(const int4*)(eh + e4);
    int4 r;
    r.x = atomicAdd(&deg0[clampN(h.x)], 1);
    r.y = atomicAdd(&deg0[clampN(h.y)], 1);
    r.z = atomicAdd(&deg0[clampN(h.z)], 1);
    r.w = atomicAdd(&deg0[clampN(h.w)], 1);
    *(int4*)(rank + e4) = r;
}

// In-block exclusive scan of 256 ints.
__global__ void scan_local(const int* __restrict__ deg0, int* __restrict__ offsets,
                           int* __restrict__ bsum) {
    int gid = blockIdx.x * 256 + threadIdx.x;
    int lane = threadIdx.x & 63, w = threadIdx.x >> 6;
    int vdeg = (gid < NN) ? deg0[gid] : 0;
    int x = vdeg;
    #pragma unroll
    for (int d = 1; d < 64; d <<= 1) {
        int y = __shfl_up(x, d, 64);
        if (lane >= d) x += y;
    }
    __shared__ int wsum[4];
    if (lane == 63) wsum[w] = x;
    __syncthreads();
    int wpre = 0;
    #pragma unroll
    for (int j = 0; j < 4; ++j) wpre += (j < w) ? wsum[j] : 0;
    int incl = x + wpre;
    if (gid < NN) offsets[gid] = incl - vdeg;
    if (threadIdx.x == 255) bsum[blockIdx.x] = incl;
}

// Each block re-scans the 235 block sums (cheap) and adds its own prefix.
__global__ void scan_add2(int* __restrict__ offsets, const int* __restrict__ bsum) {
    int tid = threadIdx.x, lane = tid & 63, w = tid >> 6;
    int vv = (tid < SCAN_B) ? bsum[tid] : 0;
    int x = vv;
    #pragma unroll
    for (int d = 1; d < 64; d <<= 1) {
        int y = __shfl_up(x, d, 64);
        if (lane >= d) x += y;
    }
    __shared__ int wsum[4];
    __shared__ int bpre;
    if (lane == 63) wsum[w] = x;
    __syncthreads();
    int wpre = 0;
    #pragma unroll
    for (int j = 0; j < 4; ++j) wpre += (j < w) ? wsum[j] : 0;
    if (tid == blockIdx.x) bpre = x + wpre - vv;   // exclusive prefix of this block
    __syncthreads();
    int gid = blockIdx.x * 256 + tid;
    if (gid < NN) offsets[gid] += bpre;
    if (gid == 0) offsets[NN] = EE;
}

// ---- merged dispatch: edge_scatter (blocks [0,EV_B)) || prep0s (rest) ----
// scatter: atomic-free permute; ONE scattered 4B (tail) store per edge.
// prep0s: node-interleaved Ytab/Ttab rows (64 halfs = all intents), zero
// row at n == NN.
__global__ void scatter_prep(const int* __restrict__ eh, const int* __restrict__ et,
                             const int* __restrict__ rank,
                             const int* __restrict__ offsets,
                             int* __restrict__ csr_tail,
                             const float* __restrict__ Gu, const float* __restrict__ Gi,
                             const int* __restrict__ deg0,
                             __half* __restrict__ Ytab, __half* __restrict__ Ttab) {
    if (blockIdx.x < EV_B) {
        int e4 = (blockIdx.x * 256 + threadIdx.x) * 4;
        if (e4 >= EE) return;
        int4 h = *(const int4*)(eh + e4);
        int4 t = *(const int4*)(et + e4);
        int4 r = *(const int4*)(rank + e4);
        int s0 = offsets[clampN(h.x)] + r.x;
        if ((unsigned)s0 < EE) csr_tail[s0] = clampN(t.x);
        int s1 = offsets[clampN(h.y)] + r.y;
        if ((unsigned)s1 < EE) csr_tail[s1] = clampN(t.y);
        int s2 = offsets[clampN(h.z)] + r.z;
        if ((unsigned)s2 < EE) csr_tail[s2] = clampN(t.z);
        int s3 = offsets[clampN(h.w)] + r.w;
        if ((unsigned)s3 < EE) csr_tail[s3] = clampN(t.w);
    } else {
        int n = (blockIdx.x - EV_B) * 4 + (threadIdx.x >> 6);
        if (n > NN) return;
        int lane = threadIdx.x & 63;            // lane == channel c
        float x = (n < NN) ? getX(Gu, Gi, n, lane) : 0.f;
        float sx = x * x;
        #pragma unroll
        for (int m = 1; m < 16; m <<= 1) sx += __shfl_xor(sx, m, 64);  // 16-ch intent group
        float invx = rsqrtf(fmaxf(sx, 1e-12f));
        float d0 = rsqrtf(fmaxf(0.25f * (float)((n < NN) ? deg0[n] : 1), 1e-30f));
        size_t a = (size_t)n * 64 + lane;
        Ytab[a] = __float2half(d0 * x);          // iter-0 Y (scores==0.25 folded)
        Ttab[a] = __float2half(tanhf(x * invx)); // tanh of l2norm(x) per intent
    }
}

// ---- zacc: Z1 accumulate + per-intent l2norm -> ZN[n][64] ----
// wave = 2 nodes x 32 half2-ch lanes; unroll-4 -> 8 full-line gathers in
// flight per wave. Also fills csr_head coalesced (heads are CSR-sorted).
__global__ void zacc(const int* __restrict__ offsets, const int* __restrict__ csr_tail,
                     const __half* __restrict__ Ytab, __half* __restrict__ ZN,
                     int* __restrict__ csr_head) {
    int tid = threadIdx.x;
    int n = blockIdx.x * 8 + (tid >> 5);
    if (n >= NN) return;
    int cc = tid & 31;                           // half2-channel (2cc, 2cc+1)
    int s0 = offsets[n], s1 = offsets[n + 1];
    for (int k = s0 + cc; k < s1; k += 32) csr_head[k] = n;  // coalesced head fill
    float accx = 0.f, accy = 0.f;
    for (int base = s0; base < s1; base += 4) {
        #pragma unroll
        for (int u = 0; u < 4; ++u) {
            int kk = base + u;
            bool act = kk < s1;
            int kc = act ? kk : s0;              // in-bounds; deg >= 1 always
            int t = act ? csr_tail[kc] : NN;     // NN = zero row
            __half2 y = *(const __half2*)(Ytab + (size_t)t * 64 + cc * 2);
            float2 yf = __half22float2(y);
            accx += yf.x; accy += yf.y;
        }
    }
    // per-intent l2 norm: 8-lane group = 16 channels = 1 intent
    float ss = accx * accx + accy * accy;
    ss += __shfl_xor(ss, 1, 64);
    ss += __shfl_xor(ss, 2, 64);
    ss += __shfl_xor(ss, 4, 64);
    float inv = rsqrtf(fmaxf(ss, 1e-12f));
    *(__half2*)(ZN + (size_t)n * 64 + cc * 2) =
        __floats2half2_rn(accx * inv, accy * inv);
}

// ---- attdot_sm: per-edge dots + per-edge softmax over intents ----
// One edge per lane, no cross-lane ops. softmax(A)=softmax(dot) since
// A = 1 + dot (shift-invariant). Stores normalized scores s4 directly
// (one 8B store per edge). v4 intermediate eliminated.
__global__ void attdot_sm(const int* __restrict__ csr_head, const int* __restrict__ csr_tail,
                          const __half* __restrict__ ZN, const __half* __restrict__ Ttab,
                          __half* __restrict__ s4) {
    int k = blockIdx.x * 256 + threadIdx.x;
    if (k >= EE) return;
    int h = csr_head[k], t = csr_tail[k];
    const float4* zp = (const float4*)(ZN + (size_t)h * 64);
    const float4* tp = (const float4*)(Ttab + (size_t)t * 64);
    float dot[4];
    #pragma unroll
    for (int i = 0; i < 4; ++i) {
        float4 za = zp[2 * i], zb = zp[2 * i + 1];
        float4 ta = tp[2 * i], tb = tp[2 * i + 1];
        __half2 acc = __floats2half2_rn(0.f, 0.f);
        acc = __hfma2(bch2(za.x), bch2(ta.x), acc);
        acc = __hfma2(bch2(za.y), bch2(ta.y), acc);
        acc = __hfma2(bch2(za.z), bch2(ta.z), acc);
        acc = __hfma2(bch2(za.w), bch2(ta.w), acc);
        acc = __hfma2(bch2(zb.x), bch2(tb.x), acc);
        acc = __hfma2(bch2(zb.y), bch2(tb.y), acc);
        acc = __hfma2(bch2(zb.z), bch2(tb.z), acc);
        acc = __hfma2(bch2(zb.w), bch2(tb.w), acc);
        float2 f = __half22float2(acc);
        dot[i] = f.x + f.y;
    }
    float mx = fmaxf(fmaxf(dot[0], dot[1]), fmaxf(dot[2], dot[3]));
    float e0 = __expf(dot[0] - mx), e1 = __expf(dot[1] - mx);
    float e2 = __expf(dot[2] - mx), e3 = __expf(dot[3] - mx);
    float inv = 1.f / (e0 + e1 + e2 + e3);
    __half2 q01 = __floats2half2_rn(e0 * inv, e1 * inv);
    __half2 q23 = __floats2half2_rn(e2 * inv, e3 * inv);
    int2 st;
    st.x = __builtin_bit_cast(int, q01);
    st.y = __builtin_bit_cast(int, q23);
    *(int2*)(s4 + (size_t)k * 4) = st;
}

// ---- deg_y1: bucket-sum of s4 -> dcol1 + Y1i row (wave per node) ----
// Pure loads + adds (softmax already done edge-parallel).
__global__ void deg_y1(const int* __restrict__ offsets, const __half* __restrict__ s4,
                       float* __restrict__ dcol1,
                       const float* __restrict__ Gu, const float* __restrict__ Gi,
                       __half* __restrict__ Y1i) {
    int n = blockIdx.x * 4 + (threadIdx.x >> 6);
    if (n >= NN) return;
    int lane = threadIdx.x & 63;
    int s0 = offsets[n], s1 = offsets[n + 1];
    float sum0 = 0.f, sum1 = 0.f, sum2 = 0.f, sum3 = 0.f;
    for (int k = s0 + lane; k < s1; k += 64) {
        int2 raw = *(const int2*)(s4 + (size_t)k * 4);
        float2 fa = __half22float2(__builtin_bit_cast(__half2, raw.x));
        float2 fb = __half22float2(__builtin_bit_cast(__half2, raw.y));
        sum0 += fa.x; sum1 += fa.y; sum2 += fb.x; sum3 += fb.y;
    }
    #pragma unroll
    for (int m = 1; m < 64; m <<= 1) {
        sum0 += __shfl_xor(sum0, m, 64);
        sum1 += __shfl_xor(sum1, m, 64);
        sum2 += __shfl_xor(sum2, m, 64);
        sum3 += __shfl_xor(sum3, m, 64);
    }
    int i = lane >> 4;                           // intent of channel 'lane'
    float dsel = (i == 0) ? sum0 : (i == 1) ? sum1 : (i == 2) ? sum2 : sum3;
    float d = rsqrtf(fmaxf(dsel, 1e-30f));
    if (lane < 4) {
        float ds = (lane == 0) ? sum0 : (lane == 1) ? sum1 : (lane == 2) ? sum2 : sum3;
        dcol1[n * 4 + lane] = rsqrtf(fmaxf(ds, 1e-30f));
    }
    float x = getX(Gu, Gi, n, lane);
    Y1i[(size_t)n * 64 + lane] = __float2half(d * x);
}

// ---- output pass: Z2 gather + finalize ----
// wave = 2 nodes x 32 half2-ch lanes (all 4 intents at once). Per edge:
// broadcast csr_tail + s4 (lane extracts its intent's half), 32 lanes
// gather one full 128B Y1i row. Single visit per edge. float2 store.
__global__ void outk(const int* __restrict__ offsets, const int* __restrict__ csr_tail,
                     const __half* __restrict__ Y1i, const __half* __restrict__ s4,
                     const float* __restrict__ dcol1,
                     const float* __restrict__ Gu, const float* __restrict__ Gi,
                     float* __restrict__ out) {
    int tid = threadIdx.x;
    int n = blockIdx.x * 8 + (tid >> 5);
    if (n >= NN) return;
    int cc = tid & 31;                           // half2-channel (2cc, 2cc+1)
    int s0 = offsets[n], s1 = offsets[n + 1];
    float accx = 0.f, accy = 0.f;
    for (int base = s0; base < s1; base += 4) {
        #pragma unroll
        for (int u = 0; u < 4; ++u) {
            int kk = base + u;
            bool act = kk < s1;
            int kc = act ? kk : s0;              // in-bounds; deg >= 1 always
            int t = csr_tail[kc];
            int2 raw = *(const int2*)(s4 + (size_t)kc * 4);
            int word = (cc & 16) ? raw.y : raw.x;
            unsigned short us = (unsigned short)(word >> ((cc & 8) ? 16 : 0));
            float s = act ? __half2float(__builtin_bit_cast(__half, us)) : 0.f;
            __half2 y = *(const __half2*)(Y1i + (size_t)t * 64 + cc * 2);
            float2 yf = __half22float2(y);
            accx = fmaf(s, yf.x, accx);
            accy = fmaf(s, yf.y, accy);
        }
    }
    float d = dcol1[n * 4 + (cc >> 3)];
    int ch = cc * 2;
    const float* xr = (n < NUSERS) ? (Gu + (size_t)n * 64 + ch)
                                   : (Gi + (size_t)(n - NUSERS) * 64 + ch);
    float2 x2 = *(const float2*)xr;
    float2 o;
    o.x = 0.5f * (x2.x + d * accx);
    o.y = 0.5f * (x2.y + d * accy);
    *(float2*)(out + (size_t)n * 64 + ch) = o;
}

// ---- launch ----

extern "C" void kernel_launch(void* const* d_in, const int* in_sizes, int n_in,
                              void* d_out, int out_size, void* d_ws, size_t ws_size,
                              hipStream_t stream) {
    const float* Gu = (const float*)d_in[0];
    const float* Gi = (const float*)d_in[1];
    const int* eh = (const int*)d_in[2];
    const int* et = (const int*)d_in[3];
    float* out = (float*)d_out;

    char* p = (char*)d_ws;
    __half* s4       = (__half*)p;     p += (size_t)EE * 4 * 2;       // 6.4 MB
    int*    csr_tail = (int*)p;        p += (size_t)EE * 4;           // 3.2 MB
    int*    csr_head = (int*)p;        p += (size_t)EE * 4;           // 3.2 MB
    int*    rank     = (int*)p;        p += (size_t)EE * 4;           // 3.2 MB
    int*    offsets  = (int*)p;        p += ((size_t)(NN + 1) * 4 + 15) / 16 * 16;
    int*    deg0     = (int*)p;        p += (size_t)NN * 4;
    int*    bsum     = (int*)p;        p += ((size_t)SCAN_B * 4 + 15) / 16 * 16;
    float*  dcol1    = (float*)p;      p += (size_t)NN * 4 * 4;
    __half* Ytab     = (__half*)p;     p += (size_t)(NN + 1) * 64 * 2; // 7.68 MB
    __half* Ttab     = (__half*)p;     p += (size_t)(NN + 1) * 64 * 2; // 7.68 MB
    __half* ZN       = (__half*)p;     // NN*64*2 = 7.68 MB -> total ~41 MB
    __half* Y1i      = Ytab;           // aliases Ytab (dead after zacc)

    const int nw_blocks = (NN + 3) / 4;

    // CSR build (rank-from-count: no cursor, no scatter atomics)
    hipMemsetAsync(deg0, 0, NN * sizeof(int), stream);
    edge_count<<<EV_B, 256, 0, stream>>>(eh, deg0, rank);
    scan_local<<<SCAN_B, 256, 0, stream>>>(deg0, offsets, bsum);
    scan_add2<<<SCAN_B, 256, 0, stream>>>(offsets, bsum);

    // atomic-free edge permute (tail-only 4B scatter) || prep tables
    scatter_prep<<<EV_B + NW1_B, 256, 0, stream>>>(eh, et, rank, offsets, csr_tail,
                                                   Gu, Gi, deg0, Ytab, Ttab);

    // iter 0: Z1 accumulate + norm + head fill, then per-edge dots+softmax
    zacc<<<N8_B, 256, 0, stream>>>(offsets, csr_tail, Ytab, ZN, csr_head);
    attdot_sm<<<(EE + 255) / 256, 256, 0, stream>>>(csr_head, csr_tail, ZN, Ttab, s4);

    // bucket sums -> dcol1 + Y1i rows
    deg_y1<<<nw_blocks, 256, 0, stream>>>(offsets, s4, dcol1, Gu, Gi, Y1i);

    // iter 1 propagate + finalize: single visit per edge, full-line gathers
    outk<<<N8_B, 256, 0, stream>>>(offsets, csr_tail, Y1i, s4, dcol1, Gu, Gi, out);
}